// Round 2
// baseline (6964.667 us; speedup 1.0000x reference)
//
#include <hip/hip_runtime.h>
#include <hip/hip_bf16.h>
#include <math.h>

// Problem constants (fixed shapes from setup_inputs)
constexpr int B_ = 16, C_ = 12, H_ = 128, W_ = 128, HID = 128;
constexpr float TAILF = 3.0f, MBWF = 0.001f, MBHF = 0.001f, MDF = 0.001f;

__device__ __forceinline__ float softplusf(float v) {
    return (v > 20.f) ? v : log1pf(expf(v));
}

// -------------------- conv1: concat(mask*x, cond) -> relu(conv3x3) --------------------
// grid = B * 64 tiles * 16 oc-groups; block 256 = 16x16 spatial tile; 8 oc per thread
__global__ __launch_bounds__(256) void conv1_relu_kern(
    const float* __restrict__ x, const float* __restrict__ cond,
    const float* __restrict__ w1, const float* __restrict__ b1,
    __hip_bfloat16* __restrict__ h1)
{
    const int ocb  = blockIdx.x & 15;
    const int tile = (blockIdx.x >> 4) & 63;
    const int b    = blockIdx.x >> 10;
    const int h0 = (tile >> 3) << 4;
    const int w0 = (tile & 7) << 4;
    const int tid = threadIdx.x;
    const int ty = tid >> 4, tx = tid & 15;

    __shared__ float s_in[16 * 18 * 18];
    for (int e = tid; e < 16 * 324; e += 256) {
        int ch = e / 324, rem = e % 324;
        int rr = rem / 18, cc = rem % 18;
        int gh = h0 + rr - 1, gw = w0 + cc - 1;
        float v = 0.f;
        if (gh >= 0 && gh < H_ && gw >= 0 && gw < W_) {
            if (ch < 12) {
                // x_frozen = mask*x, mask=1 where (h+w) odd
                v = ((gh + gw) & 1) ? x[((b * C_ + ch) * H_ + gh) * W_ + gw] : 0.f;
            } else {
                v = cond[((b * 4 + (ch - 12)) * H_ + gh) * W_ + gw];
            }
        }
        s_in[e] = v;
    }
    __syncthreads();

    float acc[8];
#pragma unroll
    for (int j = 0; j < 8; ++j) acc[j] = b1[ocb * 8 + j];

    for (int ic = 0; ic < 16; ++ic) {
#pragma unroll
        for (int kh = 0; kh < 3; ++kh)
#pragma unroll
        for (int kw = 0; kw < 3; ++kw) {
            float v = s_in[ic * 324 + (ty + kh) * 18 + (tx + kw)];
            const float* wp = &w1[((ocb * 8) * 16 + ic) * 9 + kh * 3 + kw];
#pragma unroll
            for (int j = 0; j < 8; ++j)
                acc[j] = fmaf(v, wp[j * 16 * 9], acc[j]);
        }
    }
    const int h = h0 + ty, w = w0 + tx;
#pragma unroll
    for (int j = 0; j < 8; ++j)
        h1[((b * HID + ocb * 8 + j) * H_ + h) * W_ + w] =
            __float2bfloat16(fmaxf(acc[j], 0.f));
}

// -------------------- conv2: h1 -> relu(conv3x3), 128->128 --------------------
__global__ __launch_bounds__(256) void conv2_relu_kern(
    const __hip_bfloat16* __restrict__ h1, const float* __restrict__ w2,
    const float* __restrict__ b2, __hip_bfloat16* __restrict__ h2)
{
    const int ocb  = blockIdx.x & 15;
    const int tile = (blockIdx.x >> 4) & 63;
    const int b    = blockIdx.x >> 10;
    const int h0 = (tile >> 3) << 4;
    const int w0 = (tile & 7) << 4;
    const int tid = threadIdx.x;
    const int ty = tid >> 4, tx = tid & 15;

    __shared__ float s_in[8 * 18 * 18];
    float acc[8];
#pragma unroll
    for (int j = 0; j < 8; ++j) acc[j] = b2[ocb * 8 + j];

    for (int ic0 = 0; ic0 < HID; ic0 += 8) {
        __syncthreads();
        for (int e = tid; e < 8 * 324; e += 256) {
            int ch = e / 324, rem = e % 324;
            int rr = rem / 18, cc = rem % 18;
            int gh = h0 + rr - 1, gw = w0 + cc - 1;
            float v = 0.f;
            if (gh >= 0 && gh < H_ && gw >= 0 && gw < W_)
                v = __bfloat162float(h1[((b * HID + ic0 + ch) * H_ + gh) * W_ + gw]);
            s_in[e] = v;
        }
        __syncthreads();
#pragma unroll
        for (int ic = 0; ic < 8; ++ic) {
#pragma unroll
            for (int kh = 0; kh < 3; ++kh)
#pragma unroll
            for (int kw = 0; kw < 3; ++kw) {
                float v = s_in[ic * 324 + (ty + kh) * 18 + (tx + kw)];
                const float* wp = &w2[((ocb * 8) * HID + ic0 + ic) * 9 + kh * 3 + kw];
#pragma unroll
                for (int j = 0; j < 8; ++j)
                    acc[j] = fmaf(v, wp[j * HID * 9], acc[j]);
            }
        }
    }
    const int h = h0 + ty, w = w0 + tx;
#pragma unroll
    for (int j = 0; j < 8; ++j)
        h2[((b * HID + ocb * 8 + j) * H_ + h) * W_ + w] =
            __float2bfloat16(fmaxf(acc[j], 0.f));
}

// -------------------- conv3 (active pixels only) fused with RQS --------------------
// grid = B * 32 tiles (16 rows x 32 cols); block 256 threads = 256 active pixels
__global__ __launch_bounds__(256) void conv3_rqs_kern(
    const float* __restrict__ x, const __hip_bfloat16* __restrict__ h2,
    const float* __restrict__ w3, const float* __restrict__ b3,
    float* __restrict__ xout, float* __restrict__ ws_lad)
{
    const int tile = blockIdx.x & 31;    // 8 tile-rows x 4 tile-cols
    const int b    = blockIdx.x >> 5;
    const int th0 = (tile >> 2) << 4;    // *16
    const int tw0 = (tile & 3) << 5;     // *32
    const int tid = threadIdx.x;
    const int r = tid >> 4, q = tid & 15;
    const int wa = 2 * q + (r & 1);      // active col in tile ((h+w) even)
    const int h = th0 + r;
    const int wact = tw0 + wa;
    const int wfro = tw0 + 2 * q + ((r & 1) ^ 1);

    __shared__ float s_in[8 * 18 * 34];
    __shared__ float s_red[256];

    float lad_sum = 0.f;

    for (int c = 0; c < C_; ++c) {
        float acc[23];
#pragma unroll
        for (int j = 0; j < 23; ++j) acc[j] = b3[c * 23 + j];

        for (int ic0 = 0; ic0 < HID; ic0 += 8) {
            __syncthreads();
            for (int e = tid; e < 8 * 612; e += 256) {
                int ch = e / 612, rem = e % 612;
                int rr = rem / 34, cc = rem % 34;
                int gh = th0 + rr - 1, gw = tw0 + cc - 1;
                float v = 0.f;
                if (gh >= 0 && gh < H_ && gw >= 0 && gw < W_)
                    v = __bfloat162float(h2[((b * HID + ic0 + ch) * H_ + gh) * W_ + gw]);
                s_in[e] = v;
            }
            __syncthreads();
            for (int ic = 0; ic < 8; ++ic) {
#pragma unroll
                for (int kh = 0; kh < 3; ++kh)
#pragma unroll
                for (int kw = 0; kw < 3; ++kw) {
                    float v = s_in[(ic * 18 + (r + kh)) * 34 + (wa + kw)];
                    const float* wp = &w3[((c * 23) * HID + ic0 + ic) * 9 + kh * 3 + kw];
#pragma unroll
                    for (int j = 0; j < 23; ++j)
                        acc[j] = fmaf(v, wp[j * HID * 9], acc[j]);
                }
            }
        }

        // ---- RQS spline for this (b,c,h,wact) ----
        float mw = acc[0];
#pragma unroll
        for (int j = 1; j < 8; ++j) mw = fmaxf(mw, acc[j]);
        float ew[8], sw = 0.f;
#pragma unroll
        for (int j = 0; j < 8; ++j) { ew[j] = expf(acc[j] - mw); sw += ew[j]; }
        float mh = acc[8];
#pragma unroll
        for (int j = 1; j < 8; ++j) mh = fmaxf(mh, acc[8 + j]);
        float eh[8], sh = 0.f;
#pragma unroll
        for (int j = 0; j < 8; ++j) { eh[j] = expf(acc[8 + j] - mh); sh += eh[j]; }

        float cwv[9], chv[9];
        cwv[0] = -TAILF; chv[0] = -TAILF;
        float cum_w = 0.f, cum_h = 0.f;
        const float invsw = 1.f / sw, invsh = 1.f / sh;
#pragma unroll
        for (int j = 0; j < 8; ++j) {
            cum_w += MBWF + (1.f - MBWF * 8.f) * ew[j] * invsw;
            cum_h += MBHF + (1.f - MBHF * 8.f) * eh[j] * invsh;
            cwv[j + 1] = 2.f * TAILF * cum_w - TAILF;
            chv[j + 1] = 2.f * TAILF * cum_h - TAILF;
        }
        cwv[8] = TAILF; chv[8] = TAILF;

        float dv[9];
        dv[0] = 1.f; dv[8] = 1.f;
#pragma unroll
        for (int j = 1; j < 8; ++j) dv[j] = MDF + softplusf(acc[15 + j]); // ud[j-1]

        const int base = ((b * C_ + c) * H_ + h) * W_;
        const float xa = x[base + wact];
        const float xc = fminf(fmaxf(xa, -TAILF), TAILF);
        int cnt = 0;
#pragma unroll
        for (int i = 0; i < 9; ++i) cnt += (xc >= cwv[i]) ? 1 : 0;
        int idx = cnt - 1;
        idx = idx < 0 ? 0 : (idx > 7 ? 7 : idx);

        float icw = cwv[0], iwd = cwv[1] - cwv[0];
        float ich = chv[0], ihd = chv[1] - chv[0];
        float idl = dv[0], idr = dv[1];
#pragma unroll
        for (int i = 1; i < 8; ++i) {
            if (idx == i) {
                icw = cwv[i]; iwd = cwv[i + 1] - cwv[i];
                ich = chv[i]; ihd = chv[i + 1] - chv[i];
                idl = dv[i];  idr = dv[i + 1];
            }
        }
        const float delta = ihd / iwd;
        const float th  = (xc - icw) / iwd;
        const float th1 = 1.f - th;
        const float num = ihd * (delta * th * th + idl * th * th1);
        const float den = delta + (idl + idr - 2.f * delta) * th * th1;
        float y = ich + num / den;
        const float dnum = delta * delta *
            (idr * th * th + 2.f * delta * th * th1 + idl * th1 * th1);
        float lad = logf(dnum) - 2.f * logf(den);
        const bool inside = (xa >= -TAILF) && (xa <= TAILF);
        y = inside ? y : xa;
        lad = inside ? lad : 0.f;

        xout[base + wact] = y;
        xout[base + wfro] = x[base + wfro];   // frozen passthrough
        lad_sum += lad;
    }

    // deterministic block reduction of lad
    s_red[tid] = lad_sum;
    __syncthreads();
    for (int s = 128; s > 0; s >>= 1) {
        if (tid < s) s_red[tid] += s_red[tid + s];
        __syncthreads();
    }
    if (tid == 0) ws_lad[blockIdx.x] = s_red[0];
}

// -------------------- logdet final reduce (deterministic) --------------------
__global__ void logdet_reduce_kern(const float* __restrict__ ws_lad,
                                   const float* __restrict__ logdet_in,
                                   float* __restrict__ out)
{
    int b = threadIdx.x;
    if (b < B_) {
        float s = logdet_in[b];
        for (int i = 0; i < 32; ++i) s += ws_lad[b * 32 + i];
        out[(size_t)B_ * C_ * H_ * W_ + b] = s;
    }
}

extern "C" void kernel_launch(void* const* d_in, const int* in_sizes, int n_in,
                              void* d_out, int out_size, void* d_ws, size_t ws_size,
                              hipStream_t stream) {
    const float* x    = (const float*)d_in[0];
    const float* ld   = (const float*)d_in[1];
    const float* cond = (const float*)d_in[2];
    const float* w1   = (const float*)d_in[3];
    const float* b1   = (const float*)d_in[4];
    const float* w2   = (const float*)d_in[5];
    const float* b2   = (const float*)d_in[6];
    const float* w3   = (const float*)d_in[7];
    const float* b3   = (const float*)d_in[8];
    float* out = (float*)d_out;

    // workspace layout (total exactly 128 MiB):
    //   h1 bf16 [B*HID*H*W]  (64 MiB)   -- dead after conv2
    //   h2 bf16 [B*HID*H*W]  (64 MiB)
    //   ws_lad aliases h1's storage (h1 is dead when conv3 writes partials)
    const size_t NELEM = (size_t)B_ * HID * H_ * W_;  // 2^25
    __hip_bfloat16* h1 = (__hip_bfloat16*)d_ws;
    __hip_bfloat16* h2 = h1 + NELEM;
    float* ws_lad = (float*)d_ws;   // aliases h1 region (dead by conv3)

    hipLaunchKernelGGL(conv1_relu_kern, dim3(16 * 64 * 16), dim3(256), 0, stream,
                       x, cond, w1, b1, h1);
    hipLaunchKernelGGL(conv2_relu_kern, dim3(16 * 64 * 16), dim3(256), 0, stream,
                       h1, w2, b2, h2);
    hipLaunchKernelGGL(conv3_rqs_kern, dim3(16 * 32), dim3(256), 0, stream,
                       x, h2, w3, b3, out, ws_lad);
    hipLaunchKernelGGL(logdet_reduce_kern, dim3(1), dim3(64), 0, stream,
                       ws_lad, ld, out);
}

// Round 3
// 4902.406 us; speedup vs baseline: 1.4207x; 1.4207x over previous
//
#include <hip/hip_runtime.h>
#include <hip/hip_bf16.h>
#include <math.h>

// Problem constants (fixed shapes from setup_inputs)
constexpr int B_ = 16, C_ = 12, H_ = 128, W_ = 128, HID = 128;
constexpr float TAILF = 3.0f, MBWF = 0.001f, MBHF = 0.001f, MDF = 0.001f;

__device__ __forceinline__ float softplusf(float v) {
    return (v > 20.f) ? v : log1pf(expf(v));
}

// -------------------- conv1: concat(mask*x, cond) -> relu(conv3x3) --------------------
// grid = B * 64 tiles * 16 oc-groups; block 256 = 16x16 spatial tile; 8 oc per thread
__global__ __launch_bounds__(256) void conv1_relu_kern(
    const float* __restrict__ x, const float* __restrict__ cond,
    const float* __restrict__ w1, const float* __restrict__ b1,
    __hip_bfloat16* __restrict__ h1)
{
    const int ocb  = blockIdx.x & 15;
    const int tile = (blockIdx.x >> 4) & 63;
    const int b    = blockIdx.x >> 10;
    const int h0 = (tile >> 3) << 4;
    const int w0 = (tile & 7) << 4;
    const int tid = threadIdx.x;
    const int ty = tid >> 4, tx = tid & 15;

    __shared__ float s_in[16 * 18 * 18];
    for (int e = tid; e < 16 * 324; e += 256) {
        int ch = e / 324, rem = e % 324;
        int rr = rem / 18, cc = rem % 18;
        int gh = h0 + rr - 1, gw = w0 + cc - 1;
        float v = 0.f;
        if (gh >= 0 && gh < H_ && gw >= 0 && gw < W_) {
            if (ch < 12) {
                // x_frozen = mask*x, mask=1 where (h+w) odd
                v = ((gh + gw) & 1) ? x[((b * C_ + ch) * H_ + gh) * W_ + gw] : 0.f;
            } else {
                v = cond[((b * 4 + (ch - 12)) * H_ + gh) * W_ + gw];
            }
        }
        s_in[e] = v;
    }
    __syncthreads();

    float acc[8];
#pragma unroll
    for (int j = 0; j < 8; ++j) acc[j] = b1[ocb * 8 + j];

    for (int ic = 0; ic < 16; ++ic) {
#pragma unroll
        for (int kh = 0; kh < 3; ++kh)
#pragma unroll
        for (int kw = 0; kw < 3; ++kw) {
            float v = s_in[ic * 324 + (ty + kh) * 18 + (tx + kw)];
            const float* wp = &w1[((ocb * 8) * 16 + ic) * 9 + kh * 3 + kw];
#pragma unroll
            for (int j = 0; j < 8; ++j)
                acc[j] = fmaf(v, wp[j * 16 * 9], acc[j]);
        }
    }
    const int h = h0 + ty, w = w0 + tx;
#pragma unroll
    for (int j = 0; j < 8; ++j)
        h1[((b * HID + ocb * 8 + j) * H_ + h) * W_ + w] =
            __float2bfloat16(fmaxf(acc[j], 0.f));
}

// -------------------- conv2: h1 -> relu(conv3x3), 128->128 --------------------
__global__ __launch_bounds__(256) void conv2_relu_kern(
    const __hip_bfloat16* __restrict__ h1, const float* __restrict__ w2,
    const float* __restrict__ b2, __hip_bfloat16* __restrict__ h2)
{
    const int ocb  = blockIdx.x & 15;
    const int tile = (blockIdx.x >> 4) & 63;
    const int b    = blockIdx.x >> 10;
    const int h0 = (tile >> 3) << 4;
    const int w0 = (tile & 7) << 4;
    const int tid = threadIdx.x;
    const int ty = tid >> 4, tx = tid & 15;

    __shared__ float s_in[8 * 18 * 18];
    float acc[8];
#pragma unroll
    for (int j = 0; j < 8; ++j) acc[j] = b2[ocb * 8 + j];

    for (int ic0 = 0; ic0 < HID; ic0 += 8) {
        __syncthreads();
        for (int e = tid; e < 8 * 324; e += 256) {
            int ch = e / 324, rem = e % 324;
            int rr = rem / 18, cc = rem % 18;
            int gh = h0 + rr - 1, gw = w0 + cc - 1;
            float v = 0.f;
            if (gh >= 0 && gh < H_ && gw >= 0 && gw < W_)
                v = __bfloat162float(h1[((b * HID + ic0 + ch) * H_ + gh) * W_ + gw]);
            s_in[e] = v;
        }
        __syncthreads();
#pragma unroll
        for (int ic = 0; ic < 8; ++ic) {
#pragma unroll
            for (int kh = 0; kh < 3; ++kh)
#pragma unroll
            for (int kw = 0; kw < 3; ++kw) {
                float v = s_in[ic * 324 + (ty + kh) * 18 + (tx + kw)];
                const float* wp = &w2[((ocb * 8) * HID + ic0 + ic) * 9 + kh * 3 + kw];
#pragma unroll
                for (int j = 0; j < 8; ++j)
                    acc[j] = fmaf(v, wp[j * HID * 9], acc[j]);
            }
        }
    }
    const int h = h0 + ty, w = w0 + tx;
#pragma unroll
    for (int j = 0; j < 8; ++j)
        h2[((b * HID + ocb * 8 + j) * H_ + h) * W_ + w] =
            __float2bfloat16(fmaxf(acc[j], 0.f));
}

// -------------------- conv3 (active pixels only) fused with RQS --------------------
// grid = B * 32 tiles * 12 channels; block 256 threads = 256 active pixels, 1 channel
__global__ __launch_bounds__(256) void conv3_rqs_kern(
    const float* __restrict__ x, const __hip_bfloat16* __restrict__ h2,
    const float* __restrict__ w3, const float* __restrict__ b3,
    float* __restrict__ xout, float* __restrict__ ws_lad)
{
    const int c    = blockIdx.x % 12;
    const int t    = blockIdx.x / 12;
    const int tile = t & 31;             // 8 tile-rows x 4 tile-cols
    const int b    = t >> 5;
    const int th0 = (tile >> 2) << 4;    // *16
    const int tw0 = (tile & 3) << 5;     // *32
    const int tid = threadIdx.x;
    const int r = tid >> 4, q = tid & 15;
    const int wa = 2 * q + (r & 1);      // active col in tile ((h+w) even)
    const int h = th0 + r;
    const int wact = tw0 + wa;
    const int wfro = tw0 + 2 * q + ((r & 1) ^ 1);

    __shared__ float s_in[8 * 18 * 34];
    __shared__ float s_red[256];

    float acc[23];
#pragma unroll
    for (int j = 0; j < 23; ++j) acc[j] = b3[c * 23 + j];

    for (int ic0 = 0; ic0 < HID; ic0 += 8) {
        __syncthreads();
        for (int e = tid; e < 8 * 612; e += 256) {
            int ch = e / 612, rem = e % 612;
            int rr = rem / 34, cc = rem % 34;
            int gh = th0 + rr - 1, gw = tw0 + cc - 1;
            float v = 0.f;
            if (gh >= 0 && gh < H_ && gw >= 0 && gw < W_)
                v = __bfloat162float(h2[((b * HID + ic0 + ch) * H_ + gh) * W_ + gw]);
            s_in[e] = v;
        }
        __syncthreads();
        for (int ic = 0; ic < 8; ++ic) {
#pragma unroll
            for (int kh = 0; kh < 3; ++kh)
#pragma unroll
            for (int kw = 0; kw < 3; ++kw) {
                float v = s_in[(ic * 18 + (r + kh)) * 34 + (wa + kw)];
                const float* wp = &w3[((c * 23) * HID + ic0 + ic) * 9 + kh * 3 + kw];
#pragma unroll
                for (int j = 0; j < 23; ++j)
                    acc[j] = fmaf(v, wp[j * HID * 9], acc[j]);
            }
        }
    }

    // ---- RQS spline for this (b,c,h,wact) ----
    float mw = acc[0];
#pragma unroll
    for (int j = 1; j < 8; ++j) mw = fmaxf(mw, acc[j]);
    float ew[8], sw = 0.f;
#pragma unroll
    for (int j = 0; j < 8; ++j) { ew[j] = expf(acc[j] - mw); sw += ew[j]; }
    float mh = acc[8];
#pragma unroll
    for (int j = 1; j < 8; ++j) mh = fmaxf(mh, acc[8 + j]);
    float eh[8], sh = 0.f;
#pragma unroll
    for (int j = 0; j < 8; ++j) { eh[j] = expf(acc[8 + j] - mh); sh += eh[j]; }

    float cwv[9], chv[9];
    cwv[0] = -TAILF; chv[0] = -TAILF;
    float cum_w = 0.f, cum_h = 0.f;
    const float invsw = 1.f / sw, invsh = 1.f / sh;
#pragma unroll
    for (int j = 0; j < 8; ++j) {
        cum_w += MBWF + (1.f - MBWF * 8.f) * ew[j] * invsw;
        cum_h += MBHF + (1.f - MBHF * 8.f) * eh[j] * invsh;
        cwv[j + 1] = 2.f * TAILF * cum_w - TAILF;
        chv[j + 1] = 2.f * TAILF * cum_h - TAILF;
    }
    cwv[8] = TAILF; chv[8] = TAILF;

    float dv[9];
    dv[0] = 1.f; dv[8] = 1.f;
#pragma unroll
    for (int j = 1; j < 8; ++j) dv[j] = MDF + softplusf(acc[15 + j]); // ud[j-1]

    const int base = ((b * C_ + c) * H_ + h) * W_;
    const float xa = x[base + wact];
    const float xc = fminf(fmaxf(xa, -TAILF), TAILF);
    int cnt = 0;
#pragma unroll
    for (int i = 0; i < 9; ++i) cnt += (xc >= cwv[i]) ? 1 : 0;
    int idx = cnt - 1;
    idx = idx < 0 ? 0 : (idx > 7 ? 7 : idx);

    float icw = cwv[0], iwd = cwv[1] - cwv[0];
    float ich = chv[0], ihd = chv[1] - chv[0];
    float idl = dv[0], idr = dv[1];
#pragma unroll
    for (int i = 1; i < 8; ++i) {
        if (idx == i) {
            icw = cwv[i]; iwd = cwv[i + 1] - cwv[i];
            ich = chv[i]; ihd = chv[i + 1] - chv[i];
            idl = dv[i];  idr = dv[i + 1];
        }
    }
    const float delta = ihd / iwd;
    const float th  = (xc - icw) / iwd;
    const float th1 = 1.f - th;
    const float num = ihd * (delta * th * th + idl * th * th1);
    const float den = delta + (idl + idr - 2.f * delta) * th * th1;
    float y = ich + num / den;
    const float dnum = delta * delta *
        (idr * th * th + 2.f * delta * th * th1 + idl * th1 * th1);
    float lad = logf(dnum) - 2.f * logf(den);
    const bool inside = (xa >= -TAILF) && (xa <= TAILF);
    y = inside ? y : xa;
    lad = inside ? lad : 0.f;

    xout[base + wact] = y;
    xout[base + wfro] = x[base + wfro];   // frozen passthrough

    // deterministic block reduction of lad
    s_red[tid] = lad;
    __syncthreads();
    for (int s = 128; s > 0; s >>= 1) {
        if (tid < s) s_red[tid] += s_red[tid + s];
        __syncthreads();
    }
    if (tid == 0) ws_lad[blockIdx.x] = s_red[0];
}

// -------------------- logdet final reduce (deterministic) --------------------
__global__ void logdet_reduce_kern(const float* __restrict__ ws_lad,
                                   const float* __restrict__ logdet_in,
                                   float* __restrict__ out)
{
    int b = threadIdx.x;
    if (b < B_) {
        float s = logdet_in[b];
        for (int i = 0; i < 384; ++i) s += ws_lad[b * 384 + i];
        out[(size_t)B_ * C_ * H_ * W_ + b] = s;
    }
}

extern "C" void kernel_launch(void* const* d_in, const int* in_sizes, int n_in,
                              void* d_out, int out_size, void* d_ws, size_t ws_size,
                              hipStream_t stream) {
    const float* x    = (const float*)d_in[0];
    const float* ld   = (const float*)d_in[1];
    const float* cond = (const float*)d_in[2];
    const float* w1   = (const float*)d_in[3];
    const float* b1   = (const float*)d_in[4];
    const float* w2   = (const float*)d_in[5];
    const float* b2   = (const float*)d_in[6];
    const float* w3   = (const float*)d_in[7];
    const float* b3   = (const float*)d_in[8];
    float* out = (float*)d_out;

    // workspace layout (total exactly 128 MiB):
    //   h1 bf16 [B*HID*H*W]  (64 MiB)   -- dead after conv2
    //   h2 bf16 [B*HID*H*W]  (64 MiB)
    //   ws_lad aliases h1's storage (h1 is dead when conv3 writes partials)
    const size_t NELEM = (size_t)B_ * HID * H_ * W_;  // 2^25
    __hip_bfloat16* h1 = (__hip_bfloat16*)d_ws;
    __hip_bfloat16* h2 = h1 + NELEM;
    float* ws_lad = (float*)d_ws;   // aliases h1 region (dead by conv3)

    hipLaunchKernelGGL(conv1_relu_kern, dim3(16 * 64 * 16), dim3(256), 0, stream,
                       x, cond, w1, b1, h1);
    hipLaunchKernelGGL(conv2_relu_kern, dim3(16 * 64 * 16), dim3(256), 0, stream,
                       h1, w2, b2, h2);
    hipLaunchKernelGGL(conv3_rqs_kern, dim3(16 * 32 * 12), dim3(256), 0, stream,
                       x, h2, w3, b3, out, ws_lad);
    hipLaunchKernelGGL(logdet_reduce_kern, dim3(1), dim3(64), 0, stream,
                       ws_lad, ld, out);
}

// Round 4
// 581.653 us; speedup vs baseline: 11.9739x; 8.4284x over previous
//
#include <hip/hip_runtime.h>
#include <hip/hip_bf16.h>
#include <math.h>

constexpr int B_ = 16, C_ = 12, H_ = 128, W_ = 128, HID = 128;
constexpr float TAILF = 3.0f, MBWF = 0.001f, MBHF = 0.001f, MDF = 0.001f;

typedef __attribute__((ext_vector_type(8))) short bf16x8;
typedef __attribute__((ext_vector_type(4))) short bf16x4;
typedef __attribute__((ext_vector_type(4))) float f32x4;

__device__ __forceinline__ float softplusf(float v) {
    return (v > 20.f) ? v : log1pf(expf(v));
}
__device__ __forceinline__ short bf16bits(float v) {
    __hip_bfloat16 t = __float2bfloat16(v);
    return *reinterpret_cast<short*>(&t);
}

// ==================== weight pack kernels ====================
// layout: [kpos 9][chunk 4][octile][lane 64][j 8]
// lane l in octile t: oc = t*16 + (l&15); k = chunk*32 + (l>>4)*8 + j
__global__ void pack_w2_kern(const float* __restrict__ w2,
                             __hip_bfloat16* __restrict__ wp) {
    int e = blockIdx.x * 256 + threadIdx.x;       // 9*4*8*64*8 = 147456 exact
    int j = e & 7, lane = (e >> 3) & 63, mt = (e >> 9) & 7;
    int chunk = (e >> 12) & 3, kpos = e >> 14;
    int oc = mt * 16 + (lane & 15);
    int ic = chunk * 32 + (lane >> 4) * 8 + j;
    wp[e] = __float2bfloat16(w2[(oc * 128 + ic) * 9 + kpos]);
}

__global__ void pack_w3_kern(const float* __restrict__ w3,
                             __hip_bfloat16* __restrict__ wp) {
    int e = blockIdx.x * 256 + threadIdx.x;       // 9*4*18*64*8 = 331776 exact
    int j = e & 7, lane = (e >> 3) & 63;
    int rest = e >> 9;
    int mt = rest % 18; rest /= 18;
    int chunk = rest & 3, kpos = rest >> 2;
    int oc = mt * 16 + (lane & 15);
    int ic = chunk * 32 + (lane >> 4) * 8 + j;
    float v = (oc < 276) ? w3[(oc * 128 + ic) * 9 + kpos] : 0.f;
    wp[e] = __float2bfloat16(v);
}

// ==================== conv1: VALU, NHWC bf16 output ====================
// grid = B * 64 tiles * 4 oc-groups; 16x16 tile; 32 oc per thread
__global__ __launch_bounds__(256) void conv1_relu_kern(
    const float* __restrict__ x, const float* __restrict__ cond,
    const float* __restrict__ w1, const float* __restrict__ b1,
    __hip_bfloat16* __restrict__ h1)
{
    const int ocb  = blockIdx.x & 3;
    const int tile = (blockIdx.x >> 2) & 63;
    const int b    = blockIdx.x >> 8;
    const int h0 = (tile >> 3) << 4;
    const int w0 = (tile & 7) << 4;
    const int tid = threadIdx.x;
    const int ty = tid >> 4, tx = tid & 15;

    __shared__ float s_in[16 * 324];
    for (int e = tid; e < 16 * 324; e += 256) {
        int ch = e / 324, rem = e % 324;
        int rr = rem / 18, cc = rem % 18;
        int gh = h0 + rr - 1, gw = w0 + cc - 1;
        float v = 0.f;
        if (gh >= 0 && gh < H_ && gw >= 0 && gw < W_) {
            if (ch < 12) {
                v = ((gh + gw) & 1) ? x[((b * C_ + ch) * H_ + gh) * W_ + gw] : 0.f;
            } else {
                v = cond[((b * 4 + (ch - 12)) * H_ + gh) * W_ + gw];
            }
        }
        s_in[e] = v;
    }
    __syncthreads();

    float acc[32];
#pragma unroll
    for (int j = 0; j < 32; ++j) acc[j] = b1[ocb * 32 + j];

    for (int ic = 0; ic < 16; ++ic) {
#pragma unroll
        for (int kh = 0; kh < 3; ++kh)
#pragma unroll
        for (int kw = 0; kw < 3; ++kw) {
            float v = s_in[ic * 324 + (ty + kh) * 18 + (tx + kw)];
            const float* wp = &w1[((ocb * 32) * 16 + ic) * 9 + kh * 3 + kw];
#pragma unroll
            for (int j = 0; j < 32; ++j)
                acc[j] = fmaf(v, wp[j * 16 * 9], acc[j]);
        }
    }
    const int h = h0 + ty, w = w0 + tx;
    const int pix = (b * H_ + h) * W_ + w;
#pragma unroll
    for (int g = 0; g < 4; ++g) {
        bf16x8 o;
#pragma unroll
        for (int j = 0; j < 8; ++j) o[j] = bf16bits(fmaxf(acc[g * 8 + j], 0.f));
        *reinterpret_cast<bf16x8*>(&h1[(size_t)pix * HID + ocb * 32 + g * 8]) = o;
    }
}

// ==================== conv2: MFMA implicit GEMM ====================
// grid = B*256 tiles (8x8 px); 4 waves; wave: 2 octiles x 4 ntiles
__global__ __launch_bounds__(256) void conv2_mfma_kern(
    const __hip_bfloat16* __restrict__ h1,
    const __hip_bfloat16* __restrict__ wp2,
    const float* __restrict__ b2,
    __hip_bfloat16* __restrict__ h2)
{
    const int tile = blockIdx.x & 255;
    const int b    = blockIdx.x >> 8;
    const int h0 = (tile >> 4) << 3;
    const int w0 = (tile & 15) << 3;
    const int tid = threadIdx.x;
    const int wv = tid >> 6, l = tid & 63;
    const int lg = l >> 4, ln = l & 15;

    __shared__ __hip_bfloat16 sB[100 * 40];   // [pos 10x10][ic pad 40]

    f32x4 acc[2][4];
#pragma unroll
    for (int mi = 0; mi < 2; ++mi) {
        const int ocbase = (wv * 2 + mi) * 16 + lg * 4;
#pragma unroll
        for (int nt = 0; nt < 4; ++nt)
#pragma unroll
            for (int r = 0; r < 4; ++r)
                acc[mi][nt][r] = b2[ocbase + r];
    }

    for (int chunk = 0; chunk < 4; ++chunk) {
        __syncthreads();
        for (int s = tid; s < 400; s += 256) {
            int pos = s >> 2, g = s & 3;
            int ph = pos / 10, pw = pos % 10;
            int gh = h0 + ph - 1, gw = w0 + pw - 1;
            bf16x8 v = {0, 0, 0, 0, 0, 0, 0, 0};
            if (gh >= 0 && gh < H_ && gw >= 0 && gw < W_)
                v = *reinterpret_cast<const bf16x8*>(
                    &h1[(size_t)((b * H_ + gh) * W_ + gw) * HID + chunk * 32 + g * 8]);
            *reinterpret_cast<bf16x8*>(&sB[pos * 40 + g * 8]) = v;
        }
        __syncthreads();
#pragma unroll
        for (int kpos = 0; kpos < 9; ++kpos) {
            const int kh = kpos / 3, kw = kpos % 3;
            bf16x8 afr[2];
#pragma unroll
            for (int mi = 0; mi < 2; ++mi)
                afr[mi] = *reinterpret_cast<const bf16x8*>(
                    &wp2[(size_t)(((kpos * 4 + chunk) * 8 + wv * 2 + mi) * 64 + l) * 8]);
            bf16x8 bfr[4];
#pragma unroll
            for (int nt = 0; nt < 4; ++nt) {
                int px = nt * 16 + ln;
                int pos = ((px >> 3) + kh) * 10 + (px & 7) + kw;
                bfr[nt] = *reinterpret_cast<const bf16x8*>(&sB[pos * 40 + lg * 8]);
            }
#pragma unroll
            for (int mi = 0; mi < 2; ++mi)
#pragma unroll
                for (int nt = 0; nt < 4; ++nt)
                    acc[mi][nt] = __builtin_amdgcn_mfma_f32_16x16x32_bf16(
                        afr[mi], bfr[nt], acc[mi][nt], 0, 0, 0);
        }
    }
#pragma unroll
    for (int mi = 0; mi < 2; ++mi) {
#pragma unroll
        for (int nt = 0; nt < 4; ++nt) {
            int px = nt * 16 + ln;
            int h = h0 + (px >> 3), w = w0 + (px & 7);
            bf16x4 o;
#pragma unroll
            for (int r = 0; r < 4; ++r)
                o[r] = bf16bits(fmaxf(acc[mi][nt][r], 0.f));
            *reinterpret_cast<bf16x4*>(
                &h2[(size_t)((b * H_ + h) * W_ + w) * HID + (wv * 2 + mi) * 16 + lg * 4]) = o;
        }
    }
}

// ==================== conv3 (active px only) MFMA + RQS ====================
// grid = B*256 (32 row-tiles x 8 col-strips); tile = 4 rows x 16 cols = 32 active px
// M = 288 (276 padded); waves: nt = wv>>1, m-half = (wv&1)*9
__global__ __launch_bounds__(256) void conv3_rqs_kern(
    const float* __restrict__ x,
    const __hip_bfloat16* __restrict__ h2,
    const __hip_bfloat16* __restrict__ wp3,
    const float* __restrict__ b3,
    float* __restrict__ xout, float* __restrict__ ws_lad)
{
    const int t = blockIdx.x & 255;
    const int b = blockIdx.x >> 8;
    const int r0 = (t >> 3) << 2;
    const int w0 = (t & 7) << 4;
    const int tid = threadIdx.x;
    const int wv = tid >> 6, l = tid & 63;
    const int lg = l >> 4, ln = l & 15;
    const int nt = wv >> 1, m0 = (wv & 1) * 9;

    __shared__ __hip_bfloat16 sB[108 * 40];   // [pos 6x18][ic pad 40]
    __shared__ float park[288 * 36];          // [oc][px pad 36]
    __shared__ float s_red[256];

    f32x4 acc[9];
#pragma unroll
    for (int mi = 0; mi < 9; ++mi) {
#pragma unroll
        for (int r = 0; r < 4; ++r) {
            int oc = (m0 + mi) * 16 + lg * 4 + r;
            acc[mi][r] = (oc < 276) ? b3[oc] : 0.f;
        }
    }

    const int px = nt * 16 + ln;           // 0..31
    const int pr = px >> 3, paj = px & 7;
    const int pc = 2 * paj + (pr & 1);     // local active col 0..15

    for (int chunk = 0; chunk < 4; ++chunk) {
        __syncthreads();
        for (int s = tid; s < 432; s += 256) {
            int pos = s >> 2, g = s & 3;
            int ph = pos / 18, pw = pos % 18;
            int gh = r0 + ph - 1, gw = w0 + pw - 1;
            bf16x8 v = {0, 0, 0, 0, 0, 0, 0, 0};
            if (gh >= 0 && gh < H_ && gw >= 0 && gw < W_)
                v = *reinterpret_cast<const bf16x8*>(
                    &h2[(size_t)((b * H_ + gh) * W_ + gw) * HID + chunk * 32 + g * 8]);
            *reinterpret_cast<bf16x8*>(&sB[pos * 40 + g * 8]) = v;
        }
        __syncthreads();
#pragma unroll
        for (int kpos = 0; kpos < 9; ++kpos) {
            const int kh = kpos / 3, kw = kpos % 3;
            const int pos = (pr + kh) * 18 + pc + kw;
            bf16x8 bfr = *reinterpret_cast<const bf16x8*>(&sB[pos * 40 + lg * 8]);
#pragma unroll
            for (int mi = 0; mi < 9; ++mi) {
                bf16x8 afr = *reinterpret_cast<const bf16x8*>(
                    &wp3[(size_t)(((kpos * 4 + chunk) * 18 + m0 + mi) * 64 + l) * 8]);
                acc[mi] = __builtin_amdgcn_mfma_f32_16x16x32_bf16(
                    afr, bfr, acc[mi], 0, 0, 0);
            }
        }
    }
#pragma unroll
    for (int mi = 0; mi < 9; ++mi)
#pragma unroll
        for (int r = 0; r < 4; ++r)
            park[((m0 + mi) * 16 + lg * 4 + r) * 36 + px] = acc[mi][r];
    __syncthreads();

    float ladsum = 0.f;
#pragma unroll
    for (int pass = 0; pass < 2; ++pass) {
        int task = pass * 256 + tid;
        if (task < 384) {
            int c = task >> 5, qpx = task & 31;
            int r = qpx >> 3, aj = qpx & 7;
            int hh = r0 + r;
            int wwa = w0 + 2 * aj + (r & 1);
            int wwf = w0 + 2 * aj + ((r & 1) ^ 1);

            float p[23];
#pragma unroll
            for (int j = 0; j < 23; ++j) p[j] = park[(c * 23 + j) * 36 + qpx];

            float mw = p[0];
#pragma unroll
            for (int j = 1; j < 8; ++j) mw = fmaxf(mw, p[j]);
            float ew[8], sw = 0.f;
#pragma unroll
            for (int j = 0; j < 8; ++j) { ew[j] = expf(p[j] - mw); sw += ew[j]; }
            float mh = p[8];
#pragma unroll
            for (int j = 1; j < 8; ++j) mh = fmaxf(mh, p[8 + j]);
            float eh[8], sh = 0.f;
#pragma unroll
            for (int j = 0; j < 8; ++j) { eh[j] = expf(p[8 + j] - mh); sh += eh[j]; }

            float cwv[9], chv[9];
            cwv[0] = -TAILF; chv[0] = -TAILF;
            float cum_w = 0.f, cum_h = 0.f;
            const float invsw = 1.f / sw, invsh = 1.f / sh;
#pragma unroll
            for (int j = 0; j < 8; ++j) {
                cum_w += MBWF + (1.f - MBWF * 8.f) * ew[j] * invsw;
                cum_h += MBHF + (1.f - MBHF * 8.f) * eh[j] * invsh;
                cwv[j + 1] = 2.f * TAILF * cum_w - TAILF;
                chv[j + 1] = 2.f * TAILF * cum_h - TAILF;
            }
            cwv[8] = TAILF; chv[8] = TAILF;

            float dv[9];
            dv[0] = 1.f; dv[8] = 1.f;
#pragma unroll
            for (int j = 1; j < 8; ++j) dv[j] = MDF + softplusf(p[15 + j]);

            const int base = ((b * C_ + c) * H_ + hh) * W_;
            const float xa = x[base + wwa];
            const float xc = fminf(fmaxf(xa, -TAILF), TAILF);
            int cnt = 0;
#pragma unroll
            for (int i = 0; i < 9; ++i) cnt += (xc >= cwv[i]) ? 1 : 0;
            int idx = cnt - 1;
            idx = idx < 0 ? 0 : (idx > 7 ? 7 : idx);

            float icw = cwv[0], iwd = cwv[1] - cwv[0];
            float ich = chv[0], ihd = chv[1] - chv[0];
            float idl = dv[0], idr = dv[1];
#pragma unroll
            for (int i = 1; i < 8; ++i) {
                if (idx == i) {
                    icw = cwv[i]; iwd = cwv[i + 1] - cwv[i];
                    ich = chv[i]; ihd = chv[i + 1] - chv[i];
                    idl = dv[i];  idr = dv[i + 1];
                }
            }
            const float delta = ihd / iwd;
            const float th  = (xc - icw) / iwd;
            const float th1 = 1.f - th;
            const float num = ihd * (delta * th * th + idl * th * th1);
            const float den = delta + (idl + idr - 2.f * delta) * th * th1;
            float y = ich + num / den;
            const float dnum = delta * delta *
                (idr * th * th + 2.f * delta * th * th1 + idl * th1 * th1);
            float lad = logf(dnum) - 2.f * logf(den);
            const bool inside = (xa >= -TAILF) && (xa <= TAILF);
            y = inside ? y : xa;
            lad = inside ? lad : 0.f;

            xout[base + wwa] = y;
            xout[base + wwf] = x[base + wwf];
            ladsum += lad;
        }
    }

    s_red[tid] = ladsum;
    __syncthreads();
    for (int s = 128; s > 0; s >>= 1) {
        if (tid < s) s_red[tid] += s_red[tid + s];
        __syncthreads();
    }
    if (tid == 0) ws_lad[blockIdx.x] = s_red[0];
}

// ==================== logdet final reduce ====================
__global__ void logdet_reduce_kern(const float* __restrict__ ws_lad,
                                   const float* __restrict__ logdet_in,
                                   float* __restrict__ out)
{
    int b = threadIdx.x;
    if (b < B_) {
        float s = logdet_in[b];
        for (int i = 0; i < 256; ++i) s += ws_lad[b * 256 + i];
        out[(size_t)B_ * C_ * H_ * W_ + b] = s;
    }
}

extern "C" void kernel_launch(void* const* d_in, const int* in_sizes, int n_in,
                              void* d_out, int out_size, void* d_ws, size_t ws_size,
                              hipStream_t stream) {
    const float* x    = (const float*)d_in[0];
    const float* ld   = (const float*)d_in[1];
    const float* cond = (const float*)d_in[2];
    const float* w1   = (const float*)d_in[3];
    const float* b1   = (const float*)d_in[4];
    const float* w2   = (const float*)d_in[5];
    const float* b2   = (const float*)d_in[6];
    const float* w3   = (const float*)d_in[7];
    const float* b3   = (const float*)d_in[8];
    float* out = (float*)d_out;

    // ws layout (exactly 128 MiB, proven safe):
    //   h1 bf16 NHWC [B,H,W,128]  [0, 64MiB)     -- dead after conv2
    //   h2 bf16 NHWC [B,H,W,128]  [64MiB, 128MiB)
    //   wp3 (648KB) aliases h1[0..]   -- packed AFTER conv2
    //   ws_lad (16KB) aliases h1+1MiB -- written during conv3
    // wp2 (288KB) lives in d_out[0..] -- fully overwritten by conv3 later
    const size_t NPIX = (size_t)B_ * H_ * W_;
    __hip_bfloat16* h1 = (__hip_bfloat16*)d_ws;
    __hip_bfloat16* h2 = h1 + NPIX * HID;
    __hip_bfloat16* wp3 = (__hip_bfloat16*)d_ws;
    float* ws_lad = (float*)((char*)d_ws + (1u << 20));
    __hip_bfloat16* wp2 = (__hip_bfloat16*)d_out;

    hipLaunchKernelGGL(pack_w2_kern, dim3(576), dim3(256), 0, stream, w2, wp2);
    hipLaunchKernelGGL(conv1_relu_kern, dim3(16 * 64 * 4), dim3(256), 0, stream,
                       x, cond, w1, b1, h1);
    hipLaunchKernelGGL(conv2_mfma_kern, dim3(16 * 256), dim3(256), 0, stream,
                       h1, wp2, b2, h2);
    hipLaunchKernelGGL(pack_w3_kern, dim3(1296), dim3(256), 0, stream, w3, wp3);
    hipLaunchKernelGGL(conv3_rqs_kern, dim3(16 * 256), dim3(256), 0, stream,
                       x, h2, wp3, b3, out, ws_lad);
    hipLaunchKernelGGL(logdet_reduce_kern, dim3(1), dim3(64), 0, stream,
                       ws_lad, ld, out);
}

// Round 5
// 361.371 us; speedup vs baseline: 19.2729x; 1.6096x over previous
//
#include <hip/hip_runtime.h>
#include <hip/hip_bf16.h>
#include <math.h>

constexpr int B_ = 16, C_ = 12, H_ = 128, W_ = 128, HID = 128;
constexpr float TAILF = 3.0f, MBWF = 0.001f, MBHF = 0.001f, MDF = 0.001f;

typedef __attribute__((ext_vector_type(8))) short bf16x8;
typedef __attribute__((ext_vector_type(4))) short bf16x4;
typedef __attribute__((ext_vector_type(4))) float f32x4;

__device__ __forceinline__ float softplusf(float v) {
    return (v > 20.f) ? v : log1pf(expf(v));
}
__device__ __forceinline__ short bf16bits(float v) {
    __hip_bfloat16 t = __float2bfloat16(v);
    return *reinterpret_cast<short*>(&t);
}

// ==================== weight pack kernels ====================
// common A-fragment layout: lane l, octile t: oc = t*16 + (l&15); k_local = (l>>4)*8 + j
__global__ void pack_w1_kern(const float* __restrict__ w1,
                             __hip_bfloat16* __restrict__ wp) {
    int e = blockIdx.x * 256 + threadIdx.x;       // 5*8*64*8 = 20480 exact
    int j = e & 7, lane = (e >> 3) & 63, mt = (e >> 9) & 7;
    int chunk = e >> 12;                          // 0..4
    int oc = mt * 16 + (lane & 15);
    int k_local = (lane >> 4) * 8 + j;            // 0..31
    int kpos = 2 * chunk + (k_local >> 4);        // 0..9 (9 invalid)
    int ic = k_local & 15;
    float v = (kpos < 9) ? w1[(oc * 16 + ic) * 9 + kpos] : 0.f;
    wp[e] = __float2bfloat16(v);
}

__global__ void pack_w2_kern(const float* __restrict__ w2,
                             __hip_bfloat16* __restrict__ wp) {
    int e = blockIdx.x * 256 + threadIdx.x;       // 9*4*8*64*8 = 147456 exact
    int j = e & 7, lane = (e >> 3) & 63, mt = (e >> 9) & 7;
    int chunk = (e >> 12) & 3, kpos = e >> 14;
    int oc = mt * 16 + (lane & 15);
    int ic = chunk * 32 + (lane >> 4) * 8 + j;
    wp[e] = __float2bfloat16(w2[(oc * 128 + ic) * 9 + kpos]);
}

__global__ void pack_w3_kern(const float* __restrict__ w3,
                             __hip_bfloat16* __restrict__ wp) {
    int e = blockIdx.x * 256 + threadIdx.x;       // 9*4*18*64*8 = 331776 exact
    int j = e & 7, lane = (e >> 3) & 63;
    int rest = e >> 9;
    int mt = rest % 18; rest /= 18;
    int chunk = rest & 3, kpos = rest >> 2;
    int oc = mt * 16 + (lane & 15);
    int ic = chunk * 32 + (lane >> 4) * 8 + j;
    float v = (oc < 276) ? w3[(oc * 128 + ic) * 9 + kpos] : 0.f;
    wp[e] = __float2bfloat16(v);
}

// ==================== conv1: MFMA implicit GEMM ====================
// grid = B*256 tiles (8x8 px); 4 waves; wave: 2 octiles x 4 ntiles
// K = 144 (16 ic x 9 kpos) = 5 chunks of 32 (kpos-pairs; chunk4 zero-padded)
__global__ __launch_bounds__(256) void conv1_mfma_kern(
    const float* __restrict__ x, const float* __restrict__ cond,
    const __hip_bfloat16* __restrict__ wp1,
    const float* __restrict__ b1,
    __hip_bfloat16* __restrict__ h1)
{
    const int tile = blockIdx.x & 255;
    const int b    = blockIdx.x >> 8;
    const int h0 = (tile >> 4) << 3;
    const int w0 = (tile & 15) << 3;
    const int tid = threadIdx.x;
    const int wv = tid >> 6, l = tid & 63;
    const int lg = l >> 4, ln = l & 15;

    __shared__ __hip_bfloat16 sB[100 * 20];   // [pos 10x10][ch pad 20]

    // stage masked-x (ch<12) + cond (ch 12..15) tile once, bf16
    for (int e = tid; e < 1600; e += 256) {
        int ch = e / 100, pos = e % 100;
        int ph = pos / 10, pw = pos % 10;
        int gh = h0 + ph - 1, gw = w0 + pw - 1;
        float v = 0.f;
        if (gh >= 0 && gh < H_ && gw >= 0 && gw < W_) {
            if (ch < 12) {
                v = ((gh + gw) & 1) ? x[((b * C_ + ch) * H_ + gh) * W_ + gw] : 0.f;
            } else {
                v = cond[((b * 4 + (ch - 12)) * H_ + gh) * W_ + gw];
            }
        }
        sB[pos * 20 + ch] = __float2bfloat16(v);
    }
    __syncthreads();

    f32x4 acc[2][4];
#pragma unroll
    for (int mi = 0; mi < 2; ++mi) {
        const int ocbase = (wv * 2 + mi) * 16 + lg * 4;
#pragma unroll
        for (int nt = 0; nt < 4; ++nt)
#pragma unroll
            for (int r = 0; r < 4; ++r)
                acc[mi][nt][r] = b1[ocbase + r];
    }

#pragma unroll
    for (int chunk = 0; chunk < 5; ++chunk) {
        const int kpos = (chunk == 4) ? 8 : (2 * chunk + (lg >> 1));
        const int kh = kpos / 3, kw = kpos % 3;
        bf16x8 afr[2];
#pragma unroll
        for (int mi = 0; mi < 2; ++mi)
            afr[mi] = *reinterpret_cast<const bf16x8*>(
                &wp1[(size_t)((chunk * 8 + wv * 2 + mi) * 64 + l) * 8]);
        bf16x8 bfr[4];
#pragma unroll
        for (int nt = 0; nt < 4; ++nt) {
            int px = nt * 16 + ln;
            int pos = ((px >> 3) + kh) * 10 + (px & 7) + kw;
            bfr[nt] = *reinterpret_cast<const bf16x8*>(&sB[pos * 20 + (lg & 1) * 8]);
        }
#pragma unroll
        for (int mi = 0; mi < 2; ++mi)
#pragma unroll
            for (int nt = 0; nt < 4; ++nt)
                acc[mi][nt] = __builtin_amdgcn_mfma_f32_16x16x32_bf16(
                    afr[mi], bfr[nt], acc[mi][nt], 0, 0, 0);
    }

#pragma unroll
    for (int mi = 0; mi < 2; ++mi) {
#pragma unroll
        for (int nt = 0; nt < 4; ++nt) {
            int px = nt * 16 + ln;
            int h = h0 + (px >> 3), w = w0 + (px & 7);
            bf16x4 o;
#pragma unroll
            for (int r = 0; r < 4; ++r)
                o[r] = bf16bits(fmaxf(acc[mi][nt][r], 0.f));
            *reinterpret_cast<bf16x4*>(
                &h1[(size_t)((b * H_ + h) * W_ + w) * HID + (wv * 2 + mi) * 16 + lg * 4]) = o;
        }
    }
}

// ==================== conv2: MFMA implicit GEMM ====================
__global__ __launch_bounds__(256) void conv2_mfma_kern(
    const __hip_bfloat16* __restrict__ h1,
    const __hip_bfloat16* __restrict__ wp2,
    const float* __restrict__ b2,
    __hip_bfloat16* __restrict__ h2)
{
    const int tile = blockIdx.x & 255;
    const int b    = blockIdx.x >> 8;
    const int h0 = (tile >> 4) << 3;
    const int w0 = (tile & 15) << 3;
    const int tid = threadIdx.x;
    const int wv = tid >> 6, l = tid & 63;
    const int lg = l >> 4, ln = l & 15;

    __shared__ __hip_bfloat16 sB[100 * 40];   // [pos 10x10][ic pad 40]

    f32x4 acc[2][4];
#pragma unroll
    for (int mi = 0; mi < 2; ++mi) {
        const int ocbase = (wv * 2 + mi) * 16 + lg * 4;
#pragma unroll
        for (int nt = 0; nt < 4; ++nt)
#pragma unroll
            for (int r = 0; r < 4; ++r)
                acc[mi][nt][r] = b2[ocbase + r];
    }

    for (int chunk = 0; chunk < 4; ++chunk) {
        __syncthreads();
        for (int s = tid; s < 400; s += 256) {
            int pos = s >> 2, g = s & 3;
            int ph = pos / 10, pw = pos % 10;
            int gh = h0 + ph - 1, gw = w0 + pw - 1;
            bf16x8 v = {0, 0, 0, 0, 0, 0, 0, 0};
            if (gh >= 0 && gh < H_ && gw >= 0 && gw < W_)
                v = *reinterpret_cast<const bf16x8*>(
                    &h1[(size_t)((b * H_ + gh) * W_ + gw) * HID + chunk * 32 + g * 8]);
            *reinterpret_cast<bf16x8*>(&sB[pos * 40 + g * 8]) = v;
        }
        __syncthreads();
#pragma unroll
        for (int kpos = 0; kpos < 9; ++kpos) {
            const int kh = kpos / 3, kw = kpos % 3;
            bf16x8 afr[2];
#pragma unroll
            for (int mi = 0; mi < 2; ++mi)
                afr[mi] = *reinterpret_cast<const bf16x8*>(
                    &wp2[(size_t)(((kpos * 4 + chunk) * 8 + wv * 2 + mi) * 64 + l) * 8]);
            bf16x8 bfr[4];
#pragma unroll
            for (int nt = 0; nt < 4; ++nt) {
                int px = nt * 16 + ln;
                int pos = ((px >> 3) + kh) * 10 + (px & 7) + kw;
                bfr[nt] = *reinterpret_cast<const bf16x8*>(&sB[pos * 40 + lg * 8]);
            }
#pragma unroll
            for (int mi = 0; mi < 2; ++mi)
#pragma unroll
                for (int nt = 0; nt < 4; ++nt)
                    acc[mi][nt] = __builtin_amdgcn_mfma_f32_16x16x32_bf16(
                        afr[mi], bfr[nt], acc[mi][nt], 0, 0, 0);
        }
    }
#pragma unroll
    for (int mi = 0; mi < 2; ++mi) {
#pragma unroll
        for (int nt = 0; nt < 4; ++nt) {
            int px = nt * 16 + ln;
            int h = h0 + (px >> 3), w = w0 + (px & 7);
            bf16x4 o;
#pragma unroll
            for (int r = 0; r < 4; ++r)
                o[r] = bf16bits(fmaxf(acc[mi][nt][r], 0.f));
            *reinterpret_cast<bf16x4*>(
                &h2[(size_t)((b * H_ + h) * W_ + w) * HID + (wv * 2 + mi) * 16 + lg * 4]) = o;
        }
    }
}

// ==================== conv3 (active px only) MFMA + RQS ====================
__global__ __launch_bounds__(256) void conv3_rqs_kern(
    const float* __restrict__ x,
    const __hip_bfloat16* __restrict__ h2,
    const __hip_bfloat16* __restrict__ wp3,
    const float* __restrict__ b3,
    float* __restrict__ xout, float* __restrict__ ws_lad)
{
    const int t = blockIdx.x & 255;
    const int b = blockIdx.x >> 8;
    const int r0 = (t >> 3) << 2;
    const int w0 = (t & 7) << 4;
    const int tid = threadIdx.x;
    const int wv = tid >> 6, l = tid & 63;
    const int lg = l >> 4, ln = l & 15;
    const int nt = wv >> 1, m0 = (wv & 1) * 9;

    __shared__ __hip_bfloat16 sB[108 * 40];   // [pos 6x18][ic pad 40]
    __shared__ float park[288 * 36];          // [oc][px pad 36]
    __shared__ float s_red[256];

    f32x4 acc[9];
#pragma unroll
    for (int mi = 0; mi < 9; ++mi) {
#pragma unroll
        for (int r = 0; r < 4; ++r) {
            int oc = (m0 + mi) * 16 + lg * 4 + r;
            acc[mi][r] = (oc < 276) ? b3[oc] : 0.f;
        }
    }

    const int px = nt * 16 + ln;           // 0..31
    const int pr = px >> 3, paj = px & 7;
    const int pc = 2 * paj + (pr & 1);     // local active col 0..15

    for (int chunk = 0; chunk < 4; ++chunk) {
        __syncthreads();
        for (int s = tid; s < 432; s += 256) {
            int pos = s >> 2, g = s & 3;
            int ph = pos / 18, pw = pos % 18;
            int gh = r0 + ph - 1, gw = w0 + pw - 1;
            bf16x8 v = {0, 0, 0, 0, 0, 0, 0, 0};
            if (gh >= 0 && gh < H_ && gw >= 0 && gw < W_)
                v = *reinterpret_cast<const bf16x8*>(
                    &h2[(size_t)((b * H_ + gh) * W_ + gw) * HID + chunk * 32 + g * 8]);
            *reinterpret_cast<bf16x8*>(&sB[pos * 40 + g * 8]) = v;
        }
        __syncthreads();
#pragma unroll
        for (int kpos = 0; kpos < 9; ++kpos) {
            const int kh = kpos / 3, kw = kpos % 3;
            const int pos = (pr + kh) * 18 + pc + kw;
            bf16x8 bfr = *reinterpret_cast<const bf16x8*>(&sB[pos * 40 + lg * 8]);
#pragma unroll
            for (int mi = 0; mi < 9; ++mi) {
                bf16x8 afr = *reinterpret_cast<const bf16x8*>(
                    &wp3[(size_t)(((kpos * 4 + chunk) * 18 + m0 + mi) * 64 + l) * 8]);
                acc[mi] = __builtin_amdgcn_mfma_f32_16x16x32_bf16(
                    afr, bfr, acc[mi], 0, 0, 0);
            }
        }
    }
#pragma unroll
    for (int mi = 0; mi < 9; ++mi)
#pragma unroll
        for (int r = 0; r < 4; ++r)
            park[((m0 + mi) * 16 + lg * 4 + r) * 36 + px] = acc[mi][r];
    __syncthreads();

    float ladsum = 0.f;
#pragma unroll
    for (int pass = 0; pass < 2; ++pass) {
        int task = pass * 256 + tid;
        if (task < 384) {
            int c = task >> 5, qpx = task & 31;
            int r = qpx >> 3, aj = qpx & 7;
            int hh = r0 + r;
            int wwa = w0 + 2 * aj + (r & 1);
            int wwf = w0 + 2 * aj + ((r & 1) ^ 1);

            float p[23];
#pragma unroll
            for (int j = 0; j < 23; ++j) p[j] = park[(c * 23 + j) * 36 + qpx];

            float mw = p[0];
#pragma unroll
            for (int j = 1; j < 8; ++j) mw = fmaxf(mw, p[j]);
            float ew[8], sw = 0.f;
#pragma unroll
            for (int j = 0; j < 8; ++j) { ew[j] = expf(p[j] - mw); sw += ew[j]; }
            float mh = p[8];
#pragma unroll
            for (int j = 1; j < 8; ++j) mh = fmaxf(mh, p[8 + j]);
            float eh[8], sh = 0.f;
#pragma unroll
            for (int j = 0; j < 8; ++j) { eh[j] = expf(p[8 + j] - mh); sh += eh[j]; }

            float cwv[9], chv[9];
            cwv[0] = -TAILF; chv[0] = -TAILF;
            float cum_w = 0.f, cum_h = 0.f;
            const float invsw = 1.f / sw, invsh = 1.f / sh;
#pragma unroll
            for (int j = 0; j < 8; ++j) {
                cum_w += MBWF + (1.f - MBWF * 8.f) * ew[j] * invsw;
                cum_h += MBHF + (1.f - MBHF * 8.f) * eh[j] * invsh;
                cwv[j + 1] = 2.f * TAILF * cum_w - TAILF;
                chv[j + 1] = 2.f * TAILF * cum_h - TAILF;
            }
            cwv[8] = TAILF; chv[8] = TAILF;

            float dv[9];
            dv[0] = 1.f; dv[8] = 1.f;
#pragma unroll
            for (int j = 1; j < 8; ++j) dv[j] = MDF + softplusf(p[15 + j]);

            const int base = ((b * C_ + c) * H_ + hh) * W_;
            const float xa = x[base + wwa];
            const float xc = fminf(fmaxf(xa, -TAILF), TAILF);
            int cnt = 0;
#pragma unroll
            for (int i = 0; i < 9; ++i) cnt += (xc >= cwv[i]) ? 1 : 0;
            int idx = cnt - 1;
            idx = idx < 0 ? 0 : (idx > 7 ? 7 : idx);

            float icw = cwv[0], iwd = cwv[1] - cwv[0];
            float ich = chv[0], ihd = chv[1] - chv[0];
            float idl = dv[0], idr = dv[1];
#pragma unroll
            for (int i = 1; i < 8; ++i) {
                if (idx == i) {
                    icw = cwv[i]; iwd = cwv[i + 1] - cwv[i];
                    ich = chv[i]; ihd = chv[i + 1] - chv[i];
                    idl = dv[i];  idr = dv[i + 1];
                }
            }
            const float delta = ihd / iwd;
            const float th  = (xc - icw) / iwd;
            const float th1 = 1.f - th;
            const float num = ihd * (delta * th * th + idl * th * th1);
            const float den = delta + (idl + idr - 2.f * delta) * th * th1;
            float y = ich + num / den;
            const float dnum = delta * delta *
                (idr * th * th + 2.f * delta * th * th1 + idl * th1 * th1);
            float lad = logf(dnum) - 2.f * logf(den);
            const bool inside = (xa >= -TAILF) && (xa <= TAILF);
            y = inside ? y : xa;
            lad = inside ? lad : 0.f;

            xout[base + wwa] = y;
            xout[base + wwf] = x[base + wwf];
            ladsum += lad;
        }
    }

    s_red[tid] = ladsum;
    __syncthreads();
    for (int s = 128; s > 0; s >>= 1) {
        if (tid < s) s_red[tid] += s_red[tid + s];
        __syncthreads();
    }
    if (tid == 0) ws_lad[blockIdx.x] = s_red[0];
}

// ==================== logdet final reduce ====================
__global__ void logdet_reduce_kern(const float* __restrict__ ws_lad,
                                   const float* __restrict__ logdet_in,
                                   float* __restrict__ out)
{
    int b = threadIdx.x;
    if (b < B_) {
        float s = logdet_in[b];
        for (int i = 0; i < 256; ++i) s += ws_lad[b * 256 + i];
        out[(size_t)B_ * C_ * H_ * W_ + b] = s;
    }
}

extern "C" void kernel_launch(void* const* d_in, const int* in_sizes, int n_in,
                              void* d_out, int out_size, void* d_ws, size_t ws_size,
                              hipStream_t stream) {
    const float* x    = (const float*)d_in[0];
    const float* ld   = (const float*)d_in[1];
    const float* cond = (const float*)d_in[2];
    const float* w1   = (const float*)d_in[3];
    const float* b1   = (const float*)d_in[4];
    const float* w2   = (const float*)d_in[5];
    const float* b2   = (const float*)d_in[6];
    const float* w3   = (const float*)d_in[7];
    const float* b3   = (const float*)d_in[8];
    float* out = (float*)d_out;

    // ws layout (exactly 128 MiB):
    //   h1 bf16 NHWC [B,H,W,128]  [0, 64MiB)     -- dead after conv2
    //   h2 bf16 NHWC [B,H,W,128]  [64MiB, 128MiB)
    //   wp3 (648KB) aliases h1[0..]   -- packed AFTER conv2
    //   ws_lad (16KB) aliases h1+1MiB -- written during conv3
    // d_out parking (fully rewritten by conv3+logdet later):
    //   wp2 (288KB) at d_out+0; wp1 (40KB) at d_out+512KB
    const size_t NPIX = (size_t)B_ * H_ * W_;
    __hip_bfloat16* h1 = (__hip_bfloat16*)d_ws;
    __hip_bfloat16* h2 = h1 + NPIX * HID;
    __hip_bfloat16* wp3 = (__hip_bfloat16*)d_ws;
    float* ws_lad = (float*)((char*)d_ws + (1u << 20));
    __hip_bfloat16* wp2 = (__hip_bfloat16*)d_out;
    __hip_bfloat16* wp1 = (__hip_bfloat16*)((char*)d_out + (1u << 19));

    hipLaunchKernelGGL(pack_w1_kern, dim3(80), dim3(256), 0, stream, w1, wp1);
    hipLaunchKernelGGL(pack_w2_kern, dim3(576), dim3(256), 0, stream, w2, wp2);
    hipLaunchKernelGGL(conv1_mfma_kern, dim3(16 * 256), dim3(256), 0, stream,
                       x, cond, wp1, b1, h1);
    hipLaunchKernelGGL(conv2_mfma_kern, dim3(16 * 256), dim3(256), 0, stream,
                       h1, wp2, b2, h2);
    hipLaunchKernelGGL(pack_w3_kern, dim3(1296), dim3(256), 0, stream, w3, wp3);
    hipLaunchKernelGGL(conv3_rqs_kern, dim3(16 * 256), dim3(256), 0, stream,
                       x, h2, wp3, b3, out, ws_lad);
    hipLaunchKernelGGL(logdet_reduce_kern, dim3(1), dim3(64), 0, stream,
                       ws_lad, ld, out);
}

// Round 6
// 350.554 us; speedup vs baseline: 19.8676x; 1.0309x over previous
//
#include <hip/hip_runtime.h>
#include <hip/hip_bf16.h>
#include <math.h>

constexpr int B_ = 16, C_ = 12, H_ = 128, W_ = 128, HID = 128;
constexpr float TAILF = 3.0f, MBWF = 0.001f, MBHF = 0.001f, MDF = 0.001f;

typedef __attribute__((ext_vector_type(8))) short bf16x8;
typedef __attribute__((ext_vector_type(4))) short bf16x4;
typedef __attribute__((ext_vector_type(4))) float f32x4;

__device__ __forceinline__ float softplusf(float v) {
    return (v > 20.f) ? v : log1pf(expf(v));
}
__device__ __forceinline__ short bf16bits(float v) {
    __hip_bfloat16 t = __float2bfloat16(v);
    return *reinterpret_cast<short*>(&t);
}

// ==================== weight pack kernels ====================
// common A-fragment layout: lane l, octile t: oc = t*16 + (l&15); k_local = (l>>4)*8 + j
__global__ void pack_w1_kern(const float* __restrict__ w1,
                             __hip_bfloat16* __restrict__ wp) {
    int e = blockIdx.x * 256 + threadIdx.x;       // 5*8*64*8 = 20480 exact
    int j = e & 7, lane = (e >> 3) & 63, mt = (e >> 9) & 7;
    int chunk = e >> 12;                          // 0..4
    int oc = mt * 16 + (lane & 15);
    int k_local = (lane >> 4) * 8 + j;            // 0..31
    int kpos = 2 * chunk + (k_local >> 4);        // 0..9 (9 invalid)
    int ic = k_local & 15;
    float v = (kpos < 9) ? w1[(oc * 16 + ic) * 9 + kpos] : 0.f;
    wp[e] = __float2bfloat16(v);
}

__global__ void pack_w2_kern(const float* __restrict__ w2,
                             __hip_bfloat16* __restrict__ wp) {
    int e = blockIdx.x * 256 + threadIdx.x;       // 9*4*8*64*8 = 147456 exact
    int j = e & 7, lane = (e >> 3) & 63, mt = (e >> 9) & 7;
    int chunk = (e >> 12) & 3, kpos = e >> 14;
    int oc = mt * 16 + (lane & 15);
    int ic = chunk * 32 + (lane >> 4) * 8 + j;
    wp[e] = __float2bfloat16(w2[(oc * 128 + ic) * 9 + kpos]);
}

// M padded to 320 (20 mt); oc >= 276 zero-filled
__global__ void pack_w3_kern(const float* __restrict__ w3,
                             __hip_bfloat16* __restrict__ wp) {
    int e = blockIdx.x * 256 + threadIdx.x;       // 9*4*20*64*8 = 368640 exact
    int j = e & 7, lane = (e >> 3) & 63;
    int rest = e >> 9;
    int mt = rest % 20; rest /= 20;
    int chunk = rest & 3, kpos = rest >> 2;
    int oc = mt * 16 + (lane & 15);
    int ic = chunk * 32 + (lane >> 4) * 8 + j;
    float v = (oc < 276) ? w3[(oc * 128 + ic) * 9 + kpos] : 0.f;
    wp[e] = __float2bfloat16(v);
}

// ==================== conv1: MFMA implicit GEMM ====================
// grid = B*256 tiles (8x8 px); 4 waves; wave: 2 octiles x 4 ntiles
// K = 144 (16 ic x 9 kpos) = 5 chunks of 32 (kpos-pairs; chunk4 zero-padded)
__global__ __launch_bounds__(256) void conv1_mfma_kern(
    const float* __restrict__ x, const float* __restrict__ cond,
    const __hip_bfloat16* __restrict__ wp1,
    const float* __restrict__ b1,
    __hip_bfloat16* __restrict__ h1)
{
    const int tile = blockIdx.x & 255;
    const int b    = blockIdx.x >> 8;
    const int h0 = (tile >> 4) << 3;
    const int w0 = (tile & 15) << 3;
    const int tid = threadIdx.x;
    const int wv = tid >> 6, l = tid & 63;
    const int lg = l >> 4, ln = l & 15;

    __shared__ __hip_bfloat16 sB[100 * 20];   // [pos 10x10][ch pad 20]

    for (int e = tid; e < 1600; e += 256) {
        int ch = e / 100, pos = e % 100;
        int ph = pos / 10, pw = pos % 10;
        int gh = h0 + ph - 1, gw = w0 + pw - 1;
        float v = 0.f;
        if (gh >= 0 && gh < H_ && gw >= 0 && gw < W_) {
            if (ch < 12) {
                v = ((gh + gw) & 1) ? x[((b * C_ + ch) * H_ + gh) * W_ + gw] : 0.f;
            } else {
                v = cond[((b * 4 + (ch - 12)) * H_ + gh) * W_ + gw];
            }
        }
        sB[pos * 20 + ch] = __float2bfloat16(v);
    }
    __syncthreads();

    f32x4 acc[2][4];
#pragma unroll
    for (int mi = 0; mi < 2; ++mi) {
        const int ocbase = (wv * 2 + mi) * 16 + lg * 4;
#pragma unroll
        for (int nt = 0; nt < 4; ++nt)
#pragma unroll
            for (int r = 0; r < 4; ++r)
                acc[mi][nt][r] = b1[ocbase + r];
    }

#pragma unroll
    for (int chunk = 0; chunk < 5; ++chunk) {
        const int kpos = (chunk == 4) ? 8 : (2 * chunk + (lg >> 1));
        const int kh = kpos / 3, kw = kpos % 3;
        bf16x8 afr[2];
#pragma unroll
        for (int mi = 0; mi < 2; ++mi)
            afr[mi] = *reinterpret_cast<const bf16x8*>(
                &wp1[(size_t)((chunk * 8 + wv * 2 + mi) * 64 + l) * 8]);
        bf16x8 bfr[4];
#pragma unroll
        for (int nt = 0; nt < 4; ++nt) {
            int px = nt * 16 + ln;
            int pos = ((px >> 3) + kh) * 10 + (px & 7) + kw;
            bfr[nt] = *reinterpret_cast<const bf16x8*>(&sB[pos * 20 + (lg & 1) * 8]);
        }
#pragma unroll
        for (int mi = 0; mi < 2; ++mi)
#pragma unroll
            for (int nt = 0; nt < 4; ++nt)
                acc[mi][nt] = __builtin_amdgcn_mfma_f32_16x16x32_bf16(
                    afr[mi], bfr[nt], acc[mi][nt], 0, 0, 0);
    }

#pragma unroll
    for (int mi = 0; mi < 2; ++mi) {
#pragma unroll
        for (int nt = 0; nt < 4; ++nt) {
            int px = nt * 16 + ln;
            int h = h0 + (px >> 3), w = w0 + (px & 7);
            bf16x4 o;
#pragma unroll
            for (int r = 0; r < 4; ++r)
                o[r] = bf16bits(fmaxf(acc[mi][nt][r], 0.f));
            *reinterpret_cast<bf16x4*>(
                &h1[(size_t)((b * H_ + h) * W_ + w) * HID + (wv * 2 + mi) * 16 + lg * 4]) = o;
        }
    }
}

// ==================== conv2: MFMA implicit GEMM ====================
__global__ __launch_bounds__(256) void conv2_mfma_kern(
    const __hip_bfloat16* __restrict__ h1,
    const __hip_bfloat16* __restrict__ wp2,
    const float* __restrict__ b2,
    __hip_bfloat16* __restrict__ h2)
{
    const int tile = blockIdx.x & 255;
    const int b    = blockIdx.x >> 8;
    const int h0 = (tile >> 4) << 3;
    const int w0 = (tile & 15) << 3;
    const int tid = threadIdx.x;
    const int wv = tid >> 6, l = tid & 63;
    const int lg = l >> 4, ln = l & 15;

    __shared__ __hip_bfloat16 sB[100 * 40];   // [pos 10x10][ic pad 40]

    f32x4 acc[2][4];
#pragma unroll
    for (int mi = 0; mi < 2; ++mi) {
        const int ocbase = (wv * 2 + mi) * 16 + lg * 4;
#pragma unroll
        for (int nt = 0; nt < 4; ++nt)
#pragma unroll
            for (int r = 0; r < 4; ++r)
                acc[mi][nt][r] = b2[ocbase + r];
    }

    for (int chunk = 0; chunk < 4; ++chunk) {
        __syncthreads();
        for (int s = tid; s < 400; s += 256) {
            int pos = s >> 2, g = s & 3;
            int ph = pos / 10, pw = pos % 10;
            int gh = h0 + ph - 1, gw = w0 + pw - 1;
            bf16x8 v = {0, 0, 0, 0, 0, 0, 0, 0};
            if (gh >= 0 && gh < H_ && gw >= 0 && gw < W_)
                v = *reinterpret_cast<const bf16x8*>(
                    &h1[(size_t)((b * H_ + gh) * W_ + gw) * HID + chunk * 32 + g * 8]);
            *reinterpret_cast<bf16x8*>(&sB[pos * 40 + g * 8]) = v;
        }
        __syncthreads();
#pragma unroll
        for (int kpos = 0; kpos < 9; ++kpos) {
            const int kh = kpos / 3, kw = kpos % 3;
            bf16x8 afr[2];
#pragma unroll
            for (int mi = 0; mi < 2; ++mi)
                afr[mi] = *reinterpret_cast<const bf16x8*>(
                    &wp2[(size_t)(((kpos * 4 + chunk) * 8 + wv * 2 + mi) * 64 + l) * 8]);
            bf16x8 bfr[4];
#pragma unroll
            for (int nt = 0; nt < 4; ++nt) {
                int px = nt * 16 + ln;
                int pos = ((px >> 3) + kh) * 10 + (px & 7) + kw;
                bfr[nt] = *reinterpret_cast<const bf16x8*>(&sB[pos * 40 + lg * 8]);
            }
#pragma unroll
            for (int mi = 0; mi < 2; ++mi)
#pragma unroll
                for (int nt = 0; nt < 4; ++nt)
                    acc[mi][nt] = __builtin_amdgcn_mfma_f32_16x16x32_bf16(
                        afr[mi], bfr[nt], acc[mi][nt], 0, 0, 0);
        }
    }
#pragma unroll
    for (int mi = 0; mi < 2; ++mi) {
#pragma unroll
        for (int nt = 0; nt < 4; ++nt) {
            int px = nt * 16 + ln;
            int h = h0 + (px >> 3), w = w0 + (px & 7);
            bf16x4 o;
#pragma unroll
            for (int r = 0; r < 4; ++r)
                o[r] = bf16bits(fmaxf(acc[mi][nt][r], 0.f));
            *reinterpret_cast<bf16x4*>(
                &h2[(size_t)((b * H_ + h) * W_ + w) * HID + (wv * 2 + mi) * 16 + lg * 4]) = o;
        }
    }
}

// ==================== conv3 (active px only) MFMA + RQS ====================
// grid = B*128 tiles (8 row-strips x 16 col-strips); tile = 16 rows x 8 cols
// = 64 active px (4 n-tiles). M padded to 320 = 20 mt; wave wv owns mt wv*5..wv*5+4.
// A:MFMA ratio 1:4. LDS: sB (14.4KB) aliased under park (41.5KB).
__global__ __launch_bounds__(256) void conv3_rqs_kern(
    const float* __restrict__ x,
    const __hip_bfloat16* __restrict__ h2,
    const __hip_bfloat16* __restrict__ wp3,
    const float* __restrict__ b3,
    float* __restrict__ xout, float* __restrict__ ws_lad)
{
    const int t = blockIdx.x & 127;
    const int b = blockIdx.x >> 7;
    const int r0 = (t >> 4) << 4;        // row strip *16
    const int w0 = (t & 15) << 3;        // col strip *8
    const int tid = threadIdx.x;
    const int wv = tid >> 6, l = tid & 63;
    const int lg = l >> 4, ln = l & 15;

    __shared__ __align__(16) float smem[288 * 36];   // park f32 [oc][px32 pad36]
    __shared__ float s_red[256];
    __hip_bfloat16* sB = (__hip_bfloat16*)smem;      // [pos 18x10][ic pad 40] (14.4KB)
    float* park = smem;

    f32x4 acc[5][4];
#pragma unroll
    for (int mi = 0; mi < 5; ++mi) {
#pragma unroll
        for (int r = 0; r < 4; ++r) {
            int oc = (wv * 5 + mi) * 16 + lg * 4 + r;
            float bv = (oc < 276) ? b3[oc] : 0.f;
#pragma unroll
            for (int nt = 0; nt < 4; ++nt) acc[mi][nt][r] = bv;
        }
    }

    for (int chunk = 0; chunk < 4; ++chunk) {
        __syncthreads();
        for (int s = tid; s < 720; s += 256) {
            int pos = s >> 2, g = s & 3;          // 180 pos x 4 groups
            int ph = pos / 10, pw = pos % 10;
            int gh = r0 + ph - 1, gw = w0 + pw - 1;
            bf16x8 v = {0, 0, 0, 0, 0, 0, 0, 0};
            if (gh >= 0 && gh < H_ && gw >= 0 && gw < W_)
                v = *reinterpret_cast<const bf16x8*>(
                    &h2[(size_t)((b * H_ + gh) * W_ + gw) * HID + chunk * 32 + g * 8]);
            *reinterpret_cast<bf16x8*>(&sB[pos * 40 + g * 8]) = v;
        }
        __syncthreads();
#pragma unroll
        for (int kpos = 0; kpos < 9; ++kpos) {
            const int kh = kpos / 3, kw = kpos % 3;
            bf16x8 bfr[4];
#pragma unroll
            for (int nt = 0; nt < 4; ++nt) {
                int px = nt * 16 + ln;
                int rr = px >> 2, a = px & 3;
                int pos = (rr + kh) * 10 + 2 * a + (rr & 1) + kw;
                bfr[nt] = *reinterpret_cast<const bf16x8*>(&sB[pos * 40 + lg * 8]);
            }
#pragma unroll
            for (int mi = 0; mi < 5; ++mi) {
                bf16x8 afr = *reinterpret_cast<const bf16x8*>(
                    &wp3[(size_t)(((kpos * 4 + chunk) * 20 + wv * 5 + mi) * 64 + l) * 8]);
#pragma unroll
                for (int nt = 0; nt < 4; ++nt)
                    acc[mi][nt] = __builtin_amdgcn_mfma_f32_16x16x32_bf16(
                        afr, bfr[nt], acc[mi][nt], 0, 0, 0);
            }
        }
    }

    float ladsum = 0.f;
#pragma unroll
    for (int phase = 0; phase < 2; ++phase) {
        __syncthreads();   // sB (phase0) / prior epilogue reads (phase1) done
#pragma unroll
        for (int mi = 0; mi < 5; ++mi)
#pragma unroll
            for (int half = 0; half < 2; ++half)
#pragma unroll
                for (int r = 0; r < 4; ++r) {
                    int oc = (wv * 5 + mi) * 16 + lg * 4 + r;
                    if (oc < 288)
                        park[oc * 36 + half * 16 + ln] = acc[mi][phase * 2 + half][r];
                }
        __syncthreads();
#pragma unroll
        for (int pass = 0; pass < 2; ++pass) {
            int task = pass * 256 + tid;
            if (task < 384) {
                int c = task >> 5, sub = task & 31;
                int px = phase * 32 + sub;
                int rr = px >> 2, a = px & 3;
                int hh = r0 + rr;
                int wwa = w0 + 2 * a + (rr & 1);
                int wwf = w0 + 2 * a + ((rr & 1) ^ 1);

                float p[23];
#pragma unroll
                for (int j = 0; j < 23; ++j) p[j] = park[(c * 23 + j) * 36 + sub];

                float mw = p[0];
#pragma unroll
                for (int j = 1; j < 8; ++j) mw = fmaxf(mw, p[j]);
                float ew[8], sw = 0.f;
#pragma unroll
                for (int j = 0; j < 8; ++j) { ew[j] = expf(p[j] - mw); sw += ew[j]; }
                float mh = p[8];
#pragma unroll
                for (int j = 1; j < 8; ++j) mh = fmaxf(mh, p[8 + j]);
                float eh[8], sh = 0.f;
#pragma unroll
                for (int j = 0; j < 8; ++j) { eh[j] = expf(p[8 + j] - mh); sh += eh[j]; }

                float cwv[9], chv[9];
                cwv[0] = -TAILF; chv[0] = -TAILF;
                float cum_w = 0.f, cum_h = 0.f;
                const float invsw = 1.f / sw, invsh = 1.f / sh;
#pragma unroll
                for (int j = 0; j < 8; ++j) {
                    cum_w += MBWF + (1.f - MBWF * 8.f) * ew[j] * invsw;
                    cum_h += MBHF + (1.f - MBHF * 8.f) * eh[j] * invsh;
                    cwv[j + 1] = 2.f * TAILF * cum_w - TAILF;
                    chv[j + 1] = 2.f * TAILF * cum_h - TAILF;
                }
                cwv[8] = TAILF; chv[8] = TAILF;

                float dv[9];
                dv[0] = 1.f; dv[8] = 1.f;
#pragma unroll
                for (int j = 1; j < 8; ++j) dv[j] = MDF + softplusf(p[15 + j]);

                const int base = ((b * C_ + c) * H_ + hh) * W_;
                const float xa = x[base + wwa];
                const float xc = fminf(fmaxf(xa, -TAILF), TAILF);
                int cnt = 0;
#pragma unroll
                for (int i = 0; i < 9; ++i) cnt += (xc >= cwv[i]) ? 1 : 0;
                int idx = cnt - 1;
                idx = idx < 0 ? 0 : (idx > 7 ? 7 : idx);

                float icw = cwv[0], iwd = cwv[1] - cwv[0];
                float ich = chv[0], ihd = chv[1] - chv[0];
                float idl = dv[0], idr = dv[1];
#pragma unroll
                for (int i = 1; i < 8; ++i) {
                    if (idx == i) {
                        icw = cwv[i]; iwd = cwv[i + 1] - cwv[i];
                        ich = chv[i]; ihd = chv[i + 1] - chv[i];
                        idl = dv[i];  idr = dv[i + 1];
                    }
                }
                const float delta = ihd / iwd;
                const float th  = (xc - icw) / iwd;
                const float th1 = 1.f - th;
                const float num = ihd * (delta * th * th + idl * th * th1);
                const float den = delta + (idl + idr - 2.f * delta) * th * th1;
                float y = ich + num / den;
                const float dnum = delta * delta *
                    (idr * th * th + 2.f * delta * th * th1 + idl * th1 * th1);
                float lad = logf(dnum) - 2.f * logf(den);
                const bool inside = (xa >= -TAILF) && (xa <= TAILF);
                y = inside ? y : xa;
                lad = inside ? lad : 0.f;

                xout[base + wwa] = y;
                xout[base + wwf] = x[base + wwf];
                ladsum += lad;
            }
        }
    }

    s_red[tid] = ladsum;
    __syncthreads();
    for (int s = 128; s > 0; s >>= 1) {
        if (tid < s) s_red[tid] += s_red[tid + s];
        __syncthreads();
    }
    if (tid == 0) ws_lad[blockIdx.x] = s_red[0];
}

// ==================== logdet final reduce ====================
__global__ void logdet_reduce_kern(const float* __restrict__ ws_lad,
                                   const float* __restrict__ logdet_in,
                                   float* __restrict__ out)
{
    int b = threadIdx.x;
    if (b < B_) {
        float s = logdet_in[b];
        for (int i = 0; i < 128; ++i) s += ws_lad[b * 128 + i];
        out[(size_t)B_ * C_ * H_ * W_ + b] = s;
    }
}

extern "C" void kernel_launch(void* const* d_in, const int* in_sizes, int n_in,
                              void* d_out, int out_size, void* d_ws, size_t ws_size,
                              hipStream_t stream) {
    const float* x    = (const float*)d_in[0];
    const float* ld   = (const float*)d_in[1];
    const float* cond = (const float*)d_in[2];
    const float* w1   = (const float*)d_in[3];
    const float* b1   = (const float*)d_in[4];
    const float* w2   = (const float*)d_in[5];
    const float* b2   = (const float*)d_in[6];
    const float* w3   = (const float*)d_in[7];
    const float* b3   = (const float*)d_in[8];
    float* out = (float*)d_out;

    // ws layout (128 MiB):
    //   h1 bf16 NHWC [B,H,W,128]  [0, 64MiB)     -- dead after conv2
    //   h2 bf16 NHWC [B,H,W,128]  [64MiB, 128MiB)
    //   wp3 (720KB) aliases h1[0..]   -- packed AFTER conv2
    //   ws_lad (8KB) aliases h1+1MiB  -- written during conv3
    // d_out parking (fully rewritten by conv3+logdet later):
    //   wp2 (288KB) at d_out+0; wp1 (40KB) at d_out+512KB
    const size_t NPIX = (size_t)B_ * H_ * W_;
    __hip_bfloat16* h1 = (__hip_bfloat16*)d_ws;
    __hip_bfloat16* h2 = h1 + NPIX * HID;
    __hip_bfloat16* wp3 = (__hip_bfloat16*)d_ws;
    float* ws_lad = (float*)((char*)d_ws + (1u << 20));
    __hip_bfloat16* wp2 = (__hip_bfloat16*)d_out;
    __hip_bfloat16* wp1 = (__hip_bfloat16*)((char*)d_out + (1u << 19));

    hipLaunchKernelGGL(pack_w1_kern, dim3(80), dim3(256), 0, stream, w1, wp1);
    hipLaunchKernelGGL(pack_w2_kern, dim3(576), dim3(256), 0, stream, w2, wp2);
    hipLaunchKernelGGL(conv1_mfma_kern, dim3(16 * 256), dim3(256), 0, stream,
                       x, cond, wp1, b1, h1);
    hipLaunchKernelGGL(conv2_mfma_kern, dim3(16 * 256), dim3(256), 0, stream,
                       h1, wp2, b2, h2);
    hipLaunchKernelGGL(pack_w3_kern, dim3(1440), dim3(256), 0, stream, w3, wp3);
    hipLaunchKernelGGL(conv3_rqs_kern, dim3(16 * 128), dim3(256), 0, stream,
                       x, h2, wp3, b3, out, ws_lad);
    hipLaunchKernelGGL(logdet_reduce_kern, dim3(1), dim3(64), 0, stream,
                       ws_lad, ld, out);
}